// Round 11
// baseline (48.911 us; speedup 1.0000x reference)
//
#include <hip/hip_runtime.h>

// LSHAttention: reference returns ONLY sticker = argsort(buckets) [B,S] int32.
// B=4, S=4096, D=1024, NR=32, 64 buckets.
//
// k1: grid 1024 = (b:4, ch:256 -> 16 tokens), 256 thr = 4 waves, full K.
//   3 blocks/CU (50.4 KB LDS), raw-asm barriers keep counted vmcnt(6) alive.
//   Thread = (tok_t:2 x8tok, r_t:4 x8r, kl:8); kq = w*8+kl covers 128k/tile.
//   acc = 8tok x 8r = 64 f32 (+rv 16 +qv ~8 => ~100 VGPR; waves_per_eu(4,4)
//   pins cap at 128 so the allocator can't squeeze to 64-and-spill as R10).
//   K-tiles of 128, double-buffered, staged via global_load_lds width=16:
//     Q LDS [16tok][32 f4] natural (hot read 8 grp x 2-way = free);
//     R LDS slot = k*8 + (rq ^ ((k>>2)&7)) via pre-swizzled DMA source
//     (perm within 128B, coalesced); hot read 4-way (minimal; accepted).
//   Schedule/tile: ISSUE(t+1) ; asm vmcnt(6)+s_barrier ; COMPUTE ;
//                  asm lgkmcnt(0)+s_barrier  (loads never drained mid-loop).
//   Epilogue: shfl_xor(1,2,4) kl-reduce, 4-slice LDS sum, argmax, 16-tok hist.
// k2: offset scan (256 chunks); k3: stable scatter (16-token chunk rank).

#define B_DIM 4
#define S_LEN 4096
#define D_DIM 1024
#define NRR 32
#define NBK 64
#define TMK 16                  // tokens per block = hist chunk
#define NCH (S_LEN / TMK)       // 256 chunks
#define NT 8                    // K-tiles of 128

typedef const __attribute__((address_space(1))) void* gas_t;
typedef __attribute__((address_space(3))) void* las_t;

__global__ void __launch_bounds__(256) __attribute__((amdgpu_waves_per_eu(4, 4)))
k1_buckets(const float* __restrict__ Q, const float* __restrict__ R,
           int* __restrict__ buckets, int* __restrict__ hist)
{
    __shared__ float4 smem4[3072];  // Q0[0,512) Q1[512,1024) R0[1024,2048) R1[2048,3072)
    __shared__ float xs[TMK * 33];
    __shared__ int cnt[NBK];

    const int t = threadIdx.x;
    const int b = blockIdx.x >> 8;
    const int ch = blockIdx.x & 255;

    const int w = t >> 6;
    const int lane = t & 63;
    const int tok_t = lane >> 5;        // 2 groups x 8 tokens
    const int r_t = (lane >> 3) & 3;    // 4 groups x 8 r (2 f4)
    const int kl = lane & 7;            // 8-way k split in wave
    const int kq = w * 8 + kl;          // k-quad within tile [0,32)
    const int dwb = t & ~63;            // wave-uniform DMA dest base (f4)
    const int rsw0 = (r_t * 2 + 0) ^ kl;
    const int rsw1 = (r_t * 2 + 1) ^ kl;
    const int qoff = tok_t * 256 + kq;  // + j*32
    const int roff = kq * 32;           // + kk*8 + rsw

    const float4* Qg4 = (const float4*)(Q + ((size_t)b * S_LEN + ch * TMK) * D_DIM);
    const float4* Rg4 = (const float4*)(R + (size_t)b * D_DIM * NRR);

#define ISSUE(TILE, D)                                                        \
    {                                                                         \
        _Pragma("unroll")                                                     \
        for (int i = 0; i < 2; ++i) {                                         \
            const int f = t + 256 * i;                                        \
            __builtin_amdgcn_global_load_lds(                                 \
                (gas_t)(Qg4 + (size_t)(f >> 5) * 256 + (TILE) * 32 + (f & 31)),\
                (las_t)&smem4[(D) * 512 + (i << 8) + dwb], 16, 0, 0);         \
        }                                                                     \
        _Pragma("unroll")                                                     \
        for (int i = 0; i < 4; ++i) {                                         \
            const int f = t + 256 * i;                                        \
            __builtin_amdgcn_global_load_lds(                                 \
                (gas_t)(Rg4 + ((size_t)(TILE) * 128 + (f >> 3)) * 8           \
                        + ((f & 7) ^ ((f >> 5) & 7))),                        \
                (las_t)&smem4[1024 + (D) * 1024 + (i << 8) + dwb], 16, 0, 0); \
        }                                                                     \
    }

#define COMPUTE(D)                                                            \
    {                                                                         \
        const float4* qb = smem4 + (D) * 512;                                 \
        const float4* rb = smem4 + 1024 + (D) * 1024;                         \
        float4 rv[4][2];                                                      \
        _Pragma("unroll")                                                     \
        for (int kk = 0; kk < 4; ++kk) {                                      \
            rv[kk][0] = rb[roff + kk * 8 + rsw0];                             \
            rv[kk][1] = rb[roff + kk * 8 + rsw1];                             \
        }                                                                     \
        _Pragma("unroll")                                                     \
        for (int j = 0; j < 8; ++j) {                                         \
            const float4 qv = qb[qoff + j * 32];                              \
            _Pragma("unroll")                                                 \
            for (int kk = 0; kk < 4; ++kk) {                                  \
                const float s = kk == 0 ? qv.x : kk == 1 ? qv.y               \
                              : kk == 2 ? qv.z : qv.w;                        \
                _Pragma("unroll")                                             \
                for (int p = 0; p < 2; ++p) {                                 \
                    acc[j][p].x = fmaf(s, rv[kk][p].x, acc[j][p].x);          \
                    acc[j][p].y = fmaf(s, rv[kk][p].y, acc[j][p].y);          \
                    acc[j][p].z = fmaf(s, rv[kk][p].z, acc[j][p].z);          \
                    acc[j][p].w = fmaf(s, rv[kk][p].w, acc[j][p].w);          \
                }                                                             \
            }                                                                 \
        }                                                                     \
    }

    float4 acc[8][2];
#pragma unroll
    for (int j = 0; j < 8; ++j) {
        acc[j][0] = make_float4(0.f, 0.f, 0.f, 0.f);
        acc[j][1] = make_float4(0.f, 0.f, 0.f, 0.f);
    }

    ISSUE(0, 0)
    for (int tau = 0; tau < NT; ++tau) {
        if (tau + 1 < NT) {
            ISSUE(tau + 1, (tau + 1) & 1)
            // my tile-tau loads done (tau+1's 6 stay in flight), then publish
            asm volatile("s_waitcnt vmcnt(6)\n\ts_barrier" ::: "memory");
        } else {
            asm volatile("s_waitcnt vmcnt(0)\n\ts_barrier" ::: "memory");
        }
        COMPUTE(tau & 1)
        if (tau + 1 < NT) {
            // all my LDS reads of this buffer complete before anyone overwrites
            asm volatile("s_waitcnt lgkmcnt(0)\n\ts_barrier" ::: "memory");
        } else {
            __syncthreads();
        }
    }
#undef ISSUE
#undef COMPUTE

    // ---- reduce over kl (lane bits 0-2): lanes kl==0 hold wave partial ----
#pragma unroll
    for (int j = 0; j < 8; ++j)
#pragma unroll
        for (int p = 0; p < 2; ++p) {
#pragma unroll
            for (int off = 1; off < 8; off <<= 1) {
                acc[j][p].x += __shfl_xor(acc[j][p].x, off, 64);
                acc[j][p].y += __shfl_xor(acc[j][p].y, off, 64);
                acc[j][p].z += __shfl_xor(acc[j][p].z, off, 64);
                acc[j][p].w += __shfl_xor(acc[j][p].w, off, 64);
            }
        }

    if (t < NBK) cnt[t] = 0;
    // ---- dump 4 wave-slices [16 tok][8 rq f4] into smem4[0,512) ----
    if (kl == 0) {
#pragma unroll
        for (int j = 0; j < 8; ++j) {
            const int tok = tok_t * 8 + j;
            smem4[w * 128 + tok * 8 + r_t * 2 + 0] = acc[j][0];
            smem4[w * 128 + tok * 8 + r_t * 2 + 1] = acc[j][1];
        }
    }
    __syncthreads();

    // ---- sum 4 slices (128 f4 positions) ----
    if (t < 128) {
        float4 s = smem4[t];
#pragma unroll
        for (int ww = 1; ww < 4; ++ww) {
            const float4 v = smem4[ww * 128 + t];
            s.x += v.x; s.y += v.y; s.z += v.z; s.w += v.w;
        }
        const int tok = t >> 3, rq = t & 7;
        xs[tok * 33 + rq * 4 + 0] = s.x;
        xs[tok * 33 + rq * 4 + 1] = s.y;
        xs[tok * 33 + rq * 4 + 2] = s.z;
        xs[tok * 33 + rq * 4 + 3] = s.w;
    }
    __syncthreads();

    if (t < TMK) {
        // argmax(concat[xR,-xR]) with first-occurrence tie-break
        float m1 = xs[t * 33 + 0]; int i1 = 0;
        float m2 = m1;             int i2 = 0;
#pragma unroll
        for (int r = 1; r < NRR; ++r) {
            const float v = xs[t * 33 + r];
            if (v > m1) { m1 = v; i1 = r; }
            if (v < m2) { m2 = v; i2 = r; }
        }
        const int bk = (m1 >= -m2) ? i1 : (NRR + i2);
        buckets[(size_t)b * S_LEN + ch * TMK + t] = bk;
        atomicAdd(&cnt[bk], 1);
    }
    __syncthreads();
    if (t < NBK) hist[((size_t)b * NCH + ch) * NBK + t] = cnt[t];
}

// One block, 256 threads: thread = (batch b = t/64, bucket bk = t%64).
__global__ __launch_bounds__(256) void k2_scan(
    const int* __restrict__ hist, int* __restrict__ chunkOffset)
{
    const int t = threadIdx.x;
    const int b = t >> 6;
    const int bk = t & 63;
    const int lane = t & 63;

    int total = 0;
    for (int c = 0; c < NCH; ++c)
        total += hist[((size_t)b * NCH + c) * NBK + bk];

    int incl = total;
#pragma unroll
    for (int off = 1; off < 64; off <<= 1) {
        int n = __shfl_up(incl, off, 64);
        if (lane >= off) incl += n;
    }
    int run = incl - total;   // exclusive prefix over buckets = bucketStart

    for (int c = 0; c < NCH; ++c) {
        int h = hist[((size_t)b * NCH + c) * NBK + bk];
        chunkOffset[((size_t)b * NCH + c) * NBK + bk] = run;
        run += h;
    }
}

// Stable scatter: 16-token chunks; rank via ballot within own 16-lane subgroup.
__global__ __launch_bounds__(256) void k3_scatter(
    const int* __restrict__ buckets, const int* __restrict__ chunkOffset,
    int* __restrict__ out)
{
    const int gid = blockIdx.x * 256 + threadIdx.x;  // 0..16383
    const int b = gid >> 12;
    const int s = gid & (S_LEN - 1);
    const int chunk = s >> 4;                        // 16-token chunk
    const int lane = threadIdx.x & 63;

    const int bk = buckets[gid];

    unsigned long long m = ~0ull;
#pragma unroll
    for (int i = 0; i < 6; ++i) {
        unsigned long long bi = __ballot((bk >> i) & 1);
        m &= ((bk >> i) & 1) ? bi : ~bi;
    }
    const unsigned int m16 = (unsigned int)((m >> (lane & 48)) & 0xFFFFull);
    const int rank = __popc(m16 & ((1u << (lane & 15)) - 1u));

    const int pos = chunkOffset[((size_t)b * NCH + chunk) * NBK + bk] + rank;
    out[(size_t)b * S_LEN + pos] = s;
}

extern "C" void kernel_launch(void* const* d_in, const int* in_sizes, int n_in,
                              void* d_out, int out_size, void* d_ws, size_t ws_size,
                              hipStream_t stream) {
    const float* Q = (const float*)d_in[0];
    // d_in[1] = key, d_in[2] = value: dead code in the reference, never read.
    const float* R = (const float*)d_in[3];

    int* buckets     = (int*)d_ws;                      // 16384 ints
    int* hist        = buckets + B_DIM * S_LEN;         // 4*256*64 = 65536 ints
    int* chunkOffset = hist + B_DIM * NCH * NBK;        // 65536 ints

    k1_buckets<<<B_DIM * NCH, 256, 0, stream>>>(Q, R, buckets, hist);
    k2_scan   <<<1,           256, 0, stream>>>(hist, chunkOffset);
    k3_scatter<<<(B_DIM * S_LEN) / 256, 256, 0, stream>>>(buckets, chunkOffset, (int*)d_out);
}

// Round 12
// 39.981 us; speedup vs baseline: 1.2234x; 1.2234x over previous
//
#include <hip/hip_runtime.h>

// LSHAttention: reference returns ONLY sticker = argsort(buckets) [B,S] int32.
// B=4, S=4096, D=1024, NR=32, 64 buckets.
//
// k1: grid 256 = (b:4, chunk:64 -> 64 tokens) = 1 block/CU. 256 thr = 4 waves,
//   wave = 16 tokens, FULL K. NO barriers in the main loop:
//     R (k-half, 64 KB) in shared LDS, staged twice (3 block barriers total);
//     Q streams through WAVE-PRIVATE double buffers (4 KB each) via
//     global_load_lds, self-paced with per-wave counted vmcnt(4).
//   Lane = (tok_t:2 x8tok, r_t:4 x8r, kl:8 x8k); acc = 8x8 = 64 f32.
//   Swizzles (both-sides, pre-swizzled DMA source per T21):
//     Q slot s -> s ^ tok_t        : read 8 grp x 2-way = free
//     R f4 v  -> v ^ ((k>>3)&7)    : read uniform 4-way (minimal possible)
//   Epilogue fully in-register: kl-butterfly, r_t shfl-merge argmax with
//   first-index tie-break, bucket + LDS hist. No partials, no combine kernel.
// k2/k3: 64-token-chunk scan + stable scatter (verified round 1, verbatim).

#define B_DIM 4
#define S_LEN 4096
#define D_DIM 1024
#define NRR 32
#define NBK 64
#define TMK 64                  // tokens per block = hist chunk
#define NCHUNK (S_LEN / TMK)    // 64
#define QB 4096                 // f4 offset of Q buffers in smem4

typedef const __attribute__((address_space(1))) void* gas_t;
typedef __attribute__((address_space(3))) void* las_t;

#define FMA4(A, S, B)                                                        \
    (A).x = fmaf((S), (B).x, (A).x); (A).y = fmaf((S), (B).y, (A).y);        \
    (A).z = fmaf((S), (B).z, (A).z); (A).w = fmaf((S), (B).w, (A).w);

__global__ void __launch_bounds__(256) __attribute__((amdgpu_waves_per_eu(1, 1)))
k1_buckets(const float* __restrict__ Q, const float* __restrict__ R,
           int* __restrict__ buckets, int* __restrict__ hist)
{
    __shared__ float4 smem4[QB + 2048];   // R half 64KB + 4 waves x 2 x 4KB Q
    __shared__ int cnt[NBK];

    const int t = threadIdx.x;
    const int b = blockIdx.x >> 6;
    const int chunk = blockIdx.x & 63;

    const int w = t >> 6;
    const int lane = t & 63;
    const int tok_t = lane >> 5;         // 8 tokens each
    const int r_t = (lane >> 3) & 3;     // 8 r each (2 f4)
    const int kl = lane & 7;             // 8 k each per 64k tile

    const float4* Qw4 = (const float4*)(Q + ((size_t)b * S_LEN + chunk * TMK + w * 16) * D_DIM);
    const float4* Rg4 = (const float4*)(R + (size_t)b * D_DIM * NRR);

#define STAGE_R(H)                                                            \
    {                                                                         \
        _Pragma("unroll")                                                     \
        for (int i = 0; i < 16; ++i) {                                        \
            const int rel = w * 1024 + i * 64 + lane;                         \
            const int kh = rel >> 3, v = rel & 7;                             \
            __builtin_amdgcn_global_load_lds(                                 \
                (gas_t)(Rg4 + ((size_t)(H) * 512 + kh) * 8 + (v ^ ((kh >> 3) & 7))), \
                (las_t)&smem4[w * 1024 + i * 64], 16, 0, 0);                  \
        }                                                                     \
    }

#define ISSUE_Q(H, TILE, DST)                                                 \
    {                                                                         \
        _Pragma("unroll")                                                     \
        for (int i = 0; i < 4; ++i) {                                         \
            const int f = i * 64 + lane;                                      \
            const int td = f >> 4, sd = f & 15;                               \
            __builtin_amdgcn_global_load_lds(                                 \
                (gas_t)(Qw4 + (size_t)td * 256 + (H) * 128 + (TILE) * 16      \
                        + (sd ^ (td >> 3))),                                  \
                (las_t)&smem4[QB + w * 512 + (DST) * 256 + i * 64], 16, 0, 0);\
        }                                                                     \
    }

#define COMPUTE(TILE, BUF)                                                    \
    {                                                                         \
        const float4* qb = smem4 + QB + w * 512 + (BUF) * 256;                \
        const float4* rb = smem4;                                             \
        _Pragma("unroll")                                                     \
        for (int kap = 0; kap < 2; ++kap) {                                   \
            float4 qv[8];                                                     \
            _Pragma("unroll")                                                 \
            for (int j = 0; j < 8; ++j)                                       \
                qv[j] = qb[(tok_t * 8 + j) * 16 + (((kl << 1) + kap) ^ tok_t)];\
            _Pragma("unroll")                                                 \
            for (int c = 0; c < 4; ++c) {                                     \
                const int krow = (TILE) * 64 + kl * 8 + kap * 4 + c;          \
                const float4 rv0 = rb[krow * 8 + ((r_t * 2 + 0) ^ kl)];       \
                const float4 rv1 = rb[krow * 8 + ((r_t * 2 + 1) ^ kl)];       \
                _Pragma("unroll")                                             \
                for (int j = 0; j < 8; ++j) {                                 \
                    const float s = c == 0 ? qv[j].x : c == 1 ? qv[j].y       \
                                  : c == 2 ? qv[j].z : qv[j].w;               \
                    FMA4(acc[j][0], s, rv0);                                  \
                    FMA4(acc[j][1], s, rv1);                                  \
                }                                                             \
            }                                                                 \
        }                                                                     \
    }

    float4 acc[8][2];
#pragma unroll
    for (int j = 0; j < 8; ++j) {
        acc[j][0] = make_float4(0.f, 0.f, 0.f, 0.f);
        acc[j][1] = make_float4(0.f, 0.f, 0.f, 0.f);
    }
    if (t < NBK) cnt[t] = 0;

    for (int h = 0; h < 2; ++h) {
        STAGE_R(h)                       // 16 DMA: this wave's quarter of R
        ISSUE_Q(h, 0, 0)                 // prefetch first Q tile under R stage
        asm volatile("s_waitcnt vmcnt(0)" ::: "memory");
        __syncthreads();                 // R half ready (and cnt zeroed, h==0)

        for (int tau = 0; tau < 8; ++tau) {
            if (tau < 7) {
                ISSUE_Q(h, tau + 1, (tau + 1) & 1)
                asm volatile("s_waitcnt vmcnt(4)" ::: "memory");  // my tile tau landed
            } else {
                asm volatile("s_waitcnt vmcnt(0)" ::: "memory");
            }
            COMPUTE(tau, tau & 1)        // wave-private: NO barrier
        }
        __syncthreads();                 // all waves done reading R half
    }
#undef STAGE_R
#undef ISSUE_Q
#undef COMPUTE

    // ---- butterfly reduce over kl (lane bits 0-2): all lanes get full sums ----
#pragma unroll
    for (int j = 0; j < 8; ++j)
#pragma unroll
        for (int p = 0; p < 2; ++p)
#pragma unroll
            for (int off = 1; off < 8; off <<= 1) {
                acc[j][p].x += __shfl_xor(acc[j][p].x, off, 64);
                acc[j][p].y += __shfl_xor(acc[j][p].y, off, 64);
                acc[j][p].z += __shfl_xor(acc[j][p].z, off, 64);
                acc[j][p].w += __shfl_xor(acc[j][p].w, off, 64);
            }

    // ---- in-register argmax(concat[xR,-xR]), first-occurrence tie-break ----
    int bkarr[8];
#pragma unroll
    for (int j = 0; j < 8; ++j) {
        const int rbase = r_t * 8;
        float m1 = acc[j][0].x; int i1 = rbase;
        float m2 = m1;          int i2 = rbase;
#pragma unroll
        for (int p = 0; p < 2; ++p)
#pragma unroll
            for (int c = 0; c < 4; ++c) {
                if (p == 0 && c == 0) continue;
                const float v = p == 0
                    ? (c == 1 ? acc[j][0].y : c == 2 ? acc[j][0].z : acc[j][0].w)
                    : (c == 0 ? acc[j][1].x : c == 1 ? acc[j][1].y
                              : c == 2 ? acc[j][1].z : acc[j][1].w);
                const int r = rbase + p * 4 + c;
                if (v > m1) { m1 = v; i1 = r; }
                if (v < m2) { m2 = v; i2 = r; }
            }
        // merge across the 4 r_t lanes (lane bits 3-4)
#pragma unroll
        for (int off = 8; off <= 16; off <<= 1) {
            const float om1 = __shfl_xor(m1, off, 64);
            const int   oi1 = __shfl_xor(i1, off, 64);
            const float om2 = __shfl_xor(m2, off, 64);
            const int   oi2 = __shfl_xor(i2, off, 64);
            if (om1 > m1 || (om1 == m1 && oi1 < i1)) { m1 = om1; i1 = oi1; }
            if (om2 < m2 || (om2 == m2 && oi2 < i2)) { m2 = om2; i2 = oi2; }
        }
        bkarr[j] = (m1 >= -m2) ? i1 : (NRR + i2);
    }

    if ((lane & 31) == 0) {              // lanes 0 and 32: r_t==0, kl==0
#pragma unroll
        for (int j = 0; j < 8; ++j) {
            const int gtok = chunk * TMK + w * 16 + tok_t * 8 + j;
            buckets[(size_t)b * S_LEN + gtok] = bkarr[j];
            atomicAdd(&cnt[bkarr[j]], 1);
        }
    }
    __syncthreads();
    if (t < NBK) hist[((size_t)b * NCHUNK + chunk) * NBK + t] = cnt[t];
}

// One block, 256 threads: thread = (batch b = t/64, bucket bk = t%64).
__global__ __launch_bounds__(256) void k2_scan(
    const int* __restrict__ hist, int* __restrict__ chunkOffset)
{
    const int t = threadIdx.x;
    const int b = t >> 6;
    const int bk = t & 63;
    const int lane = t & 63;

    int total = 0;
    for (int c = 0; c < NCHUNK; ++c)
        total += hist[((size_t)b * NCHUNK + c) * NBK + bk];

    int incl = total;
#pragma unroll
    for (int off = 1; off < 64; off <<= 1) {
        int n = __shfl_up(incl, off, 64);
        if (lane >= off) incl += n;
    }
    int run = incl - total;   // exclusive prefix over buckets = bucketStart

    for (int c = 0; c < NCHUNK; ++c) {
        int h = hist[((size_t)b * NCHUNK + c) * NBK + bk];
        chunkOffset[((size_t)b * NCHUNK + c) * NBK + bk] = run;
        run += h;
    }
}

// Stable scatter: wave = 64 consecutive tokens (one chunk).
__global__ __launch_bounds__(256) void k3_scatter(
    const int* __restrict__ buckets, const int* __restrict__ chunkOffset,
    int* __restrict__ out)
{
    const int gid = blockIdx.x * 256 + threadIdx.x;  // 0..16383
    const int b = gid >> 12;
    const int s = gid & (S_LEN - 1);
    const int chunk = s >> 6;
    const int lane = threadIdx.x & 63;

    const int bk = buckets[gid];

    unsigned long long m = ~0ull;
#pragma unroll
    for (int i = 0; i < 6; ++i) {
        unsigned long long bi = __ballot((bk >> i) & 1);
        m &= ((bk >> i) & 1) ? bi : ~bi;
    }
    int rank = __popcll(m & ((1ull << lane) - 1ull));

    int pos = chunkOffset[((size_t)b * NCHUNK + chunk) * NBK + bk] + rank;
    out[(size_t)b * S_LEN + pos] = s;
}

extern "C" void kernel_launch(void* const* d_in, const int* in_sizes, int n_in,
                              void* d_out, int out_size, void* d_ws, size_t ws_size,
                              hipStream_t stream) {
    const float* Q = (const float*)d_in[0];
    // d_in[1] = key, d_in[2] = value: dead code in the reference, never read.
    const float* R = (const float*)d_in[3];

    int* buckets     = (int*)d_ws;                      // 16384 ints
    int* hist        = buckets + B_DIM * S_LEN;         // 4*64*64 = 16384 ints
    int* chunkOffset = hist + B_DIM * NCHUNK * NBK;     // 16384 ints

    k1_buckets<<<B_DIM * NCHUNK, 256, 0, stream>>>(Q, R, buckets, hist);
    k2_scan   <<<1,              256, 0, stream>>>(hist, chunkOffset);
    k3_scatter<<<(B_DIM * S_LEN) / 256, 256, 0, stream>>>(buckets, chunkOffset, (int*)d_out);
}